// Round 5
// baseline (377.263 us; speedup 1.0000x reference)
//
#include <hip/hip_runtime.h>

typedef short bfrag __attribute__((ext_vector_type(8)));   // 8 bf16 (4 VGPRs)
typedef float f32x4 __attribute__((ext_vector_type(4)));   // MFMA accumulator

#define MFMA16(a, b, c) __builtin_amdgcn_mfma_f32_16x16x32_bf16((a), (b), (c), 0, 0, 0)

// b=2, s=2048, d=1024, h=16, hd=64, R=257, w=128, scale=sqrt(64)=8
#define SEQ   2048
#define DMOD  1024
#define NHEAD 16
#define HDIM  64
#define RSZ   257
#define RSTRIDE 260   // padded row stride of rp16 (8B-aligned vector stores)
#define RPADN 272     // 17*16, zero-padded
#define XN    (4096*1024)
#define WN    (3072*1024)
#define LOG2E 1.44269504f

__device__ __forceinline__ unsigned short f2bf(float f) {
  unsigned int u = __float_as_uint(f);
  u += 0x7FFFu + ((u >> 16) & 1u);   // round-to-nearest-even
  return (unsigned short)(u >> 16);
}
__device__ __forceinline__ float bf2f(unsigned short u) {
  return __uint_as_float(((unsigned int)u) << 16);
}
// packed f32x2 -> bf16x2 (single v_cvt_pk_bf16_f32 on gfx950)
__device__ __forceinline__ unsigned int pkbf(float a, float b) {
#if defined(__gfx950__)
  unsigned int r;
  asm("v_cvt_pk_bf16_f32 %0, %1, %2" : "=v"(r) : "v"(a), "v"(b));
  return r;
#else
  return (unsigned int)f2bf(a) | ((unsigned int)f2bf(b) << 16);
#endif
}
__device__ __forceinline__ float fexp2(float x) {
#if __has_builtin(__builtin_amdgcn_exp2f)
  return __builtin_amdgcn_exp2f(x);
#else
  return __expf(x * 0.69314718f);
#endif
}
__device__ __forceinline__ void gl2lds16(const void* g, void* l) {
  __builtin_amdgcn_global_load_lds(
      (__attribute__((address_space(1))) void*)(g),
      (__attribute__((address_space(3))) void*)(l), 16, 0, 0);
}

// ------------------- fused cast kernel -------------------
__global__ __launch_bounds__(256) void cast_all(const float* __restrict__ x,
                                                const float* __restrict__ Wqkv,
                                                const float* __restrict__ Wr,
                                                unsigned short* __restrict__ xb,
                                                unsigned short* __restrict__ wb,
                                                unsigned short* __restrict__ wrb) {
  int i = (blockIdx.x * 256 + threadIdx.x) * 4;
  if (i < XN) {
    float4 v = *(const float4*)(x + i);
    ushort4 o; o.x = f2bf(v.x); o.y = f2bf(v.y); o.z = f2bf(v.z); o.w = f2bf(v.w);
    *(ushort4*)(xb + i) = o;
  } else if (i < XN + WN) {
    int j = i - XN;
    float4 v = *(const float4*)(Wqkv + j);
    ushort4 o; o.x = f2bf(v.x); o.y = f2bf(v.y); o.z = f2bf(v.z); o.w = f2bf(v.w);
    *(ushort4*)(wb + j) = o;
  } else {
    int j = i - XN - WN;      // 0 .. 17407, 4 at a time
    ushort4 o;
    unsigned short t[4];
#pragma unroll
    for (int k = 0; k < 4; ++k)
      t[k] = (j + k < RSZ * HDIM) ? f2bf(Wr[j + k]) : (unsigned short)0;
    o.x = t[0]; o.y = t[1]; o.z = t[2]; o.w = t[3];
    *(ushort4*)(wrb + j) = o;
  }
}

// ------------------- QKV projection GEMM -------------------
__global__ __launch_bounds__(256) void qkv_gemm(const unsigned short* __restrict__ xb,
                                                const unsigned short* __restrict__ wb,
                                                const float* __restrict__ bqkv,
                                                unsigned short* __restrict__ qb,
                                                unsigned short* __restrict__ kbuf,
                                                unsigned short* __restrict__ vtb) {
  __shared__ unsigned short SMEM[2 * 128 * 64];   // As | Bs; reused as Vtmp
  unsigned short* As = SMEM;
  unsigned short* Bs = SMEM + 128 * 64;
  unsigned short* Vtmp = SMEM;                    // 64 x 136 bf16 (17408 B)
  const int tid = threadIdx.x;
  const int m0 = blockIdx.y * 128, n0 = blockIdx.x * 128;
  const int wave = tid >> 6, lane = tid & 63;
  const int q4 = lane >> 4, l16 = lane & 15;
  const int wm = (wave & 1) * 64, wn = (wave >> 1) * 64;
  const int sw = l16 & 7;

  f32x4 acc[4][4];
#pragma unroll
  for (int rt = 0; rt < 4; ++rt)
#pragma unroll
    for (int ct = 0; ct < 4; ++ct) acc[rt][ct] = (f32x4){0.f, 0.f, 0.f, 0.f};

  for (int k0 = 0; k0 < DMOD; k0 += 64) {
#pragma unroll
    for (int it = 0; it < 4; ++it) {
      int ch = it * 256 + tid;
      int r = ch >> 3, cl = (ch & 7) ^ (r & 7);
      gl2lds16(xb + (size_t)(m0 + r) * DMOD + k0 + cl * 8, As + ch * 8);
      gl2lds16(wb + (size_t)(n0 + r) * DMOD + k0 + cl * 8, Bs + ch * 8);
    }
    __syncthreads();
#pragma unroll
    for (int ks = 0; ks < 2; ++ks) {
      bfrag af[4], bf[4];
#pragma unroll
      for (int rt = 0; rt < 4; ++rt)
        af[rt] = *(const bfrag*)(As + (wm + rt * 16 + l16) * 64 + ((ks * 4 + q4) ^ sw) * 8);
#pragma unroll
      for (int ct = 0; ct < 4; ++ct)
        bf[ct] = *(const bfrag*)(Bs + (wn + ct * 16 + l16) * 64 + ((ks * 4 + q4) ^ sw) * 8);
      // swapped order: D rows <- bf rows (n), D cols <- af rows (m)
#pragma unroll
      for (int rt = 0; rt < 4; ++rt)
#pragma unroll
        for (int ct = 0; ct < 4; ++ct)
          acc[rt][ct] = MFMA16(bf[ct], af[rt], acc[rt][ct]);
    }
    __syncthreads();
  }

  // ---- epilogue: lane holds C[m][n..n+3]; m = wm+rt*16+l16, n = wn+ct*16+q4*4
  const int batch = m0 >> 11;
  const int sbase = m0 & 2047;
  const int r3 = blockIdx.x % 3;       // V-region pattern: period 3 tiles
  const bool hasV = (r3 != 0);
  const int nv0 = n0 + ((r3 == 2) ? 64 : 0);   // global col base of V region

#pragma unroll
  for (int ct = 0; ct < 4; ++ct) {
    int ng = n0 + wn + ct * 16 + q4 * 4;
    int hh = ng / 192;
    int rem = ng - hh * 192;
    int t = rem >> 6, dd = rem & 63;
    float4 b4 = *(const float4*)(bqkv + ng);
    if (t < 2) {
      unsigned short* dst = (t == 0) ? qb : kbuf;
      size_t rowo = ((size_t)(batch * NHEAD + hh)) * SEQ + sbase;
#pragma unroll
      for (int rt = 0; rt < 4; ++rt) {
        int m = wm + rt * 16 + l16;
        uint2 pv;
        pv.x = pkbf(acc[rt][ct][0] + b4.x, acc[rt][ct][1] + b4.y);
        pv.y = pkbf(acc[rt][ct][2] + b4.z, acc[rt][ct][3] + b4.w);
        *(uint2*)(dst + (rowo + m) * HDIM + dd) = pv;
      }
    } else {
#pragma unroll
      for (int rt = 0; rt < 4; ++rt) {
        int m = wm + rt * 16 + l16;
        Vtmp[(dd + 0) * 136 + m] = f2bf(acc[rt][ct][0] + b4.x);
        Vtmp[(dd + 1) * 136 + m] = f2bf(acc[rt][ct][1] + b4.y);
        Vtmp[(dd + 2) * 136 + m] = f2bf(acc[rt][ct][2] + b4.z);
        Vtmp[(dd + 3) * 136 + m] = f2bf(acc[rt][ct][3] + b4.w);
      }
    }
  }

  if (hasV) {
    __syncthreads();
    const int hh = nv0 / 192;
    unsigned short* vdst = vtb + ((size_t)(batch * NHEAD + hh)) * HDIM * SEQ;
#pragma unroll
    for (int it = 0; it < 4; ++it) {
      int u = it * 256 + tid;            // dd in [0,64), mc in [0,16)
      int dd = u >> 4, mc = u & 15;
      bfrag val = *(const bfrag*)(Vtmp + dd * 136 + mc * 8);
      *(bfrag*)(vdst + (size_t)dd * SEQ + sbase + mc * 8) = val;
    }
  }
}

// ------------------- rel-pos logits (transposed-D, vector stores) ---------
__global__ __launch_bounds__(256) void rp_gemm(const unsigned short* __restrict__ qb,
                                               const unsigned short* __restrict__ wrb,
                                               const float* __restrict__ br,
                                               unsigned short* __restrict__ rp16) {
  __shared__ unsigned short WrS[RPADN * HDIM];  // 34816 B
  __shared__ unsigned short Qs[64 * HDIM];      // 8192 B
  const int tid = threadIdx.x;
  const size_t row0 = (size_t)blockIdx.x * 64;

  for (int i = tid; i < RPADN * HDIM / 8; i += 256)
    *(uint4*)(&WrS[i * 8]) = *(const uint4*)(&wrb[i * 8]);
  for (int i = tid; i < 512; i += 256)
    *(uint4*)(&Qs[i * 8]) = *(const uint4*)(&qb[row0 * HDIM + i * 8]);
  __syncthreads();

  const int wave = tid >> 6, lane = tid & 63;
  const int q4 = lane >> 4, l16 = lane & 15;

  bfrag af0 = *(const bfrag*)(Qs + (wave * 16 + l16) * 64 + q4 * 8);
  bfrag af1 = *(const bfrag*)(Qs + (wave * 16 + l16) * 64 + 32 + q4 * 8);

  unsigned short* rrow = rp16 + (row0 + wave * 16 + l16) * RSTRIDE;
  const float br256 = br[256];

#pragma unroll 4
  for (int ct = 0; ct < 16; ++ct) {
    f32x4 acc = (f32x4){0.f, 0.f, 0.f, 0.f};
    bfrag w0 = *(const bfrag*)(WrS + (ct * 16 + l16) * 64 + q4 * 8);
    bfrag w1 = *(const bfrag*)(WrS + (ct * 16 + l16) * 64 + 32 + q4 * 8);
    // swapped order: D rows <- Wr rows (r), D cols <- q rows (i)
    acc = MFMA16(w0, af0, acc);
    acc = MFMA16(w1, af1, acc);
    int r = ct * 16 + q4 * 4;
    float4 b4 = *(const float4*)(br + r);
    uint2 pv;
    pv.x = pkbf((acc[0] + b4.x) * LOG2E, (acc[1] + b4.y) * LOG2E);
    pv.y = pkbf((acc[2] + b4.z) * LOG2E, (acc[3] + b4.w) * LOG2E);
    *(uint2*)(rrow + r) = pv;
  }
  // tail tile: only r = 256 is a real column
  {
    f32x4 acc = (f32x4){0.f, 0.f, 0.f, 0.f};
    bfrag w0 = *(const bfrag*)(WrS + (256 + l16) * 64 + q4 * 8);
    bfrag w1 = *(const bfrag*)(WrS + (256 + l16) * 64 + 32 + q4 * 8);
    acc = MFMA16(w0, af0, acc);
    acc = MFMA16(w1, af1, acc);
    if (q4 == 0)
      rrow[256] = f2bf((acc[0] + br256) * LOG2E);
  }
}

// ------------------- flash attention, barrier-free formulation ------------
// v5: rounds 0-3 bracket 97-110us regardless of pipelining or block count
// -> the per-tile [stage -> vmcnt(0)+barrier -> compute -> barrier] convoy
// IS the stall. Ps is wave-private (rloc strips), and with the XCD remap
// K/V (2 MB/XCD) is L2-resident. So read K and V frags DIRECTLY
// global->VGPR (wave's 64 lanes tile 16x64B sectors exactly; zero
// over-fetch) and delete all LDS staging => ZERO barriers, fully
// independent waves, compiler-pipelined loads across tiles. V frags issued
// before softmax so L2 latency hides under the exp/reduce VALU phase.
__global__ __launch_bounds__(256) void flash_attn(const unsigned short* __restrict__ qb,
                                                  const unsigned short* __restrict__ kbuf,
                                                  const unsigned short* __restrict__ vtb,
                                                  const unsigned short* __restrict__ rp16,
                                                  float* __restrict__ out) {
  __shared__ unsigned short Ps[64 * 64];   // 8192 B; wave-private 16-row strips

  const int tid = threadIdx.x;
  // XCD-aware remap: XCD g gets heads {4g..4g+3} x all 32 i-tiles ->
  // per-XCD K/V working set = 2 MB, fits the 4 MB per-XCD L2.
  const int orig = blockIdx.x;
  const int slot = orig >> 3;                 // 0..127
  const int bh = (orig & 7) * 4 + (slot >> 5);
  const int i0 = (slot & 31) << 6;
  const int wave = tid >> 6, lane = tid & 63;
  const int q4 = lane >> 4, l16 = lane & 15;
  const int sw = l16 & 7;
  const float SC = 0.125f * LOG2E;

  const int rloc = wave * 16 + l16;
  const int ig = i0 + rloc;                 // this lane's global Q row
  const int iw0 = i0 + wave * 16;           // wave's first q row
  const unsigned short* qrow = qb + ((size_t)bh * SEQ + ig) * HDIM;
  bfrag qf0 = *(const bfrag*)(qrow + q4 * 8);
  bfrag qf1 = *(const bfrag*)(qrow + 32 + q4 * 8);

  const unsigned short* rpbase = rp16 + ((size_t)bh * SEQ + ig) * RSTRIDE;
  const float rpL = bf2f(rpbase[0]);
  const float rpR = bf2f(rpbase[256]);

  float m_s = -3.0e38f, l_s = 0.f;
  f32x4 oacc[4];
#pragma unroll
  for (int ct = 0; ct < 4; ++ct) oacc[ct] = (f32x4){0.f, 0.f, 0.f, 0.f};

  // per-lane base pointers for direct K/V fragment loads
  const unsigned short* kfp = kbuf + (size_t)bh * SEQ * HDIM + (size_t)l16 * HDIM + q4 * 8;
  const unsigned short* vfp = vtb + (size_t)bh * HDIM * SEQ + (size_t)l16 * SEQ + q4 * 8;

  for (int jt = 0; jt < 32; ++jt) {
    const int j0 = jt * 64;

    // ---- K frags: global->VGPR (L2-hit). row = j0+ct*16+l16, k-half 0/1.
    bfrag kf[8];
#pragma unroll
    for (int ct = 0; ct < 4; ++ct) {
      const unsigned short* kr = kfp + (size_t)(j0 + ct * 16) * HDIM;
      kf[2 * ct]     = *(const bfrag*)(kr);
      kf[2 * ct + 1] = *(const bfrag*)(kr + 32);
    }

    // S^T = K Q^T : sacc[ct] holds S[j = ct*16+q4*4+reg][i = l16's row]
    f32x4 sacc[4];
    __builtin_amdgcn_s_setprio(1);
#pragma unroll
    for (int ct = 0; ct < 4; ++ct) {
      f32x4 z = (f32x4){0.f, 0.f, 0.f, 0.f};
      z = MFMA16(kf[2 * ct], qf0, z);
      z = MFMA16(kf[2 * ct + 1], qf1, z);
      sacc[ct] = z;
    }
    __builtin_amdgcn_s_setprio(0);

    // ---- V frags issued NOW: ~200cy L2 latency hides under softmax.
    // row d = ct*16+l16 (stride SEQ), cols j0 + half*32 + q4*8.
    bfrag vf[8];
#pragma unroll
    for (int ct = 0; ct < 4; ++ct) {
      const unsigned short* vr = vfp + (size_t)(ct * 16) * SEQ + j0;
      vf[2 * ct]     = *(const bfrag*)(vr);
      vf[2 * ct + 1] = *(const bfrag*)(vr + 32);
    }

    // logits2 = S*(log2e/8) + pos2 ; wave-uniform saturation bounds
    float p[4][4];
    const int djw = j0 - iw0;
    if (djw >= 143) {            // min(j-i) = djw-15 >= 128 -> all clamp +128
#pragma unroll
      for (int ct = 0; ct < 4; ++ct)
#pragma unroll
        for (int reg = 0; reg < 4; ++reg)
          p[ct][reg] = sacc[ct][reg] * SC + rpR;
    } else if (djw <= -191) {    // max(j-i) = djw+63 <= -128 -> all clamp -128
#pragma unroll
      for (int ct = 0; ct < 4; ++ct)
#pragma unroll
        for (int reg = 0; reg < 4; ++reg)
          p[ct][reg] = sacc[ct][reg] * SC + rpL;
    } else {
#pragma unroll
      for (int ct = 0; ct < 4; ++ct) {
#pragma unroll
        for (int reg = 0; reg < 4; ++reg) {
          int j = j0 + ct * 16 + q4 * 4 + reg;
          int off = j - ig;
          off = (off < -128) ? -128 : (off > 128 ? 128 : off);
          p[ct][reg] = sacc[ct][reg] * SC + bf2f(rpbase[off + 128]);
        }
      }
    }

    // online softmax: in-lane tree + xor16/xor32 (quads hold disjoint j's)
    float mm;
    {
      float a0 = fmaxf(fmaxf(p[0][0], p[0][1]), fmaxf(p[0][2], p[0][3]));
      float a1 = fmaxf(fmaxf(p[1][0], p[1][1]), fmaxf(p[1][2], p[1][3]));
      float a2 = fmaxf(fmaxf(p[2][0], p[2][1]), fmaxf(p[2][2], p[2][3]));
      float a3 = fmaxf(fmaxf(p[3][0], p[3][1]), fmaxf(p[3][2], p[3][3]));
      mm = fmaxf(fmaxf(a0, a1), fmaxf(a2, a3));
      mm = fmaxf(mm, __shfl_xor(mm, 16));
      mm = fmaxf(mm, __shfl_xor(mm, 32));
    }
    // defer-rescale (T13): skip O-rescale when max grows by <= 8 (log2 units)
    if (!__all(mm <= m_s + 8.0f)) {
      const float mnew = fmaxf(m_s, mm);
      const float alpha = fexp2(m_s - mnew);
      m_s = mnew;
      l_s *= alpha;
#pragma unroll
      for (int ct = 0; ct < 4; ++ct)
#pragma unroll
        for (int reg = 0; reg < 4; ++reg)
          oacc[ct][reg] *= alpha;
    }
#pragma unroll
    for (int ct = 0; ct < 4; ++ct)
#pragma unroll
      for (int reg = 0; reg < 4; ++reg)
        p[ct][reg] = fexp2(p[ct][reg] - m_s);
    {
      float s0 = (p[0][0] + p[0][1]) + (p[0][2] + p[0][3]);
      float s1 = (p[1][0] + p[1][1]) + (p[1][2] + p[1][3]);
      float s2 = (p[2][0] + p[2][1]) + (p[2][2] + p[2][3]);
      float s3 = (p[3][0] + p[3][1]) + (p[3][2] + p[3][3]);
      float rs = (s0 + s1) + (s2 + s3);
      rs += __shfl_xor(rs, 16);
      rs += __shfl_xor(rs, 32);
      l_s += rs;
    }

    // P^T -> Ps strip (wave-private; same-wave LDS ordering, NO barrier).
    unsigned int* Pw = (unsigned int*)Ps;
#pragma unroll
    for (int ct = 0; ct < 4; ++ct) {
      unsigned int pk01 = pkbf(p[ct][0], p[ct][1]);
      unsigned int pk23 = pkbf(p[ct][2], p[ct][3]);
      int chunk = ct * 2 + (q4 >> 1);
      unsigned int a = rloc * 32 + ((chunk ^ sw) << 2) + ((q4 & 1) << 1);
      Pw[a] = pk01;
      Pw[a + 1] = pk23;
    }

    // PV: out^T += V^T P^T ; pf = B-frag rows = Q rows (read own row)
    bfrag pf0 = *(const bfrag*)(Ps + rloc * 64 + (q4 ^ sw) * 8);
    bfrag pf1 = *(const bfrag*)(Ps + rloc * 64 + ((4 + q4) ^ sw) * 8);
    __builtin_amdgcn_s_setprio(1);
#pragma unroll
    for (int ct = 0; ct < 4; ++ct) {
      oacc[ct] = MFMA16(vf[2 * ct], pf0, oacc[ct]);
      oacc[ct] = MFMA16(vf[2 * ct + 1], pf1, oacc[ct]);
    }
    __builtin_amdgcn_s_setprio(0);
  }

  const int bidx = bh >> 4, hh = bh & 15;
  const float inv = 1.0f / l_s;
  float* orow = out + ((size_t)bidx * SEQ + ig) * DMOD + hh * HDIM;
#pragma unroll
  for (int ct = 0; ct < 4; ++ct) {
    float4 v;
    v.x = oacc[ct][0] * inv;
    v.y = oacc[ct][1] * inv;
    v.z = oacc[ct][2] * inv;
    v.w = oacc[ct][3] * inv;
    *(float4*)(orow + ct * 16 + q4 * 4) = v;
  }
}

// ------------------- launch -------------------
extern "C" void kernel_launch(void* const* d_in, const int* in_sizes, int n_in,
                              void* d_out, int out_size, void* d_ws, size_t ws_size,
                              hipStream_t stream) {
  const float* x    = (const float*)d_in[0];  // [2,2048,1024]
  const float* Wqkv = (const float*)d_in[1];  // [3072,1024]
  const float* bqkv = (const float*)d_in[2];  // [3072]
  const float* Wr   = (const float*)d_in[3];  // [257,64]
  const float* br   = (const float*)d_in[4];  // [257]
  float* out = (float*)d_out;                 // [2,2048,1024] fp32

  char* ws = (char*)d_ws;
  unsigned short* xb   = (unsigned short*)(ws);               // 8 MB
  unsigned short* wb   = (unsigned short*)(ws + 8388608);     // 6 MB
  unsigned short* qb   = (unsigned short*)(ws + 14680064);    // 8 MB
  unsigned short* kb   = (unsigned short*)(ws + 23068672);    // 8 MB
  unsigned short* vtb  = (unsigned short*)(ws + 31457280);    // 8 MB (transposed V)
  unsigned short* wrb  = (unsigned short*)(ws + 39845888);    // 34816 B
  unsigned short* rp16 = (unsigned short*)(ws + 39880704);    // 34.1 MB (bf16, stride 260)

  cast_all<<<7185, 256, 0, stream>>>(x, Wqkv, Wr, xb, wb, wrb);
  qkv_gemm<<<dim3(24, 32), 256, 0, stream>>>(xb, wb, bqkv, qb, kb, vtb);
  rp_gemm<<<1024, 256, 0, stream>>>(qb, wrb, br, rp16);
  flash_attn<<<1024, 256, 0, stream>>>(qb, kb, vtb, rp16, out);
}

// Round 6
// 287.837 us; speedup vs baseline: 1.3107x; 1.3107x over previous
//
#include <hip/hip_runtime.h>

typedef short bfrag __attribute__((ext_vector_type(8)));   // 8 bf16 (4 VGPRs)
typedef float f32x4 __attribute__((ext_vector_type(4)));   // MFMA accumulator

#define MFMA16(a, b, c) __builtin_amdgcn_mfma_f32_16x16x32_bf16((a), (b), (c), 0, 0, 0)

// b=2, s=2048, d=1024, h=16, hd=64, R=257, w=128, scale=sqrt(64)=8
#define SEQ   2048
#define DMOD  1024
#define NHEAD 16
#define HDIM  64
#define RSZ   257
#define RSTRIDE 260   // padded row stride of rp16 (8B-aligned vector stores)
#define RPADN 272     // 17*16, zero-padded
#define XN    (4096*1024)
#define WN    (3072*1024)
#define LOG2E 1.44269504f

__device__ __forceinline__ unsigned short f2bf(float f) {
  unsigned int u = __float_as_uint(f);
  u += 0x7FFFu + ((u >> 16) & 1u);   // round-to-nearest-even
  return (unsigned short)(u >> 16);
}
__device__ __forceinline__ float bf2f(unsigned short u) {
  return __uint_as_float(((unsigned int)u) << 16);
}
// packed f32x2 -> bf16x2 (single v_cvt_pk_bf16_f32 on gfx950)
__device__ __forceinline__ unsigned int pkbf(float a, float b) {
#if defined(__gfx950__)
  unsigned int r;
  asm("v_cvt_pk_bf16_f32 %0, %1, %2" : "=v"(r) : "v"(a), "v"(b));
  return r;
#else
  return (unsigned int)f2bf(a) | ((unsigned int)f2bf(b) << 16);
#endif
}
__device__ __forceinline__ float fexp2(float x) {
#if __has_builtin(__builtin_amdgcn_exp2f)
  return __builtin_amdgcn_exp2f(x);
#else
  return __expf(x * 0.69314718f);
#endif
}
__device__ __forceinline__ void gl2lds16(const void* g, void* l) {
  __builtin_amdgcn_global_load_lds(
      (__attribute__((address_space(1))) void*)(g),
      (__attribute__((address_space(3))) void*)(l), 16, 0, 0);
}

// ------------------- fused cast kernel -------------------
__global__ __launch_bounds__(256) void cast_all(const float* __restrict__ x,
                                                const float* __restrict__ Wqkv,
                                                const float* __restrict__ Wr,
                                                unsigned short* __restrict__ xb,
                                                unsigned short* __restrict__ wb,
                                                unsigned short* __restrict__ wrb) {
  int i = (blockIdx.x * 256 + threadIdx.x) * 4;
  if (i < XN) {
    float4 v = *(const float4*)(x + i);
    ushort4 o; o.x = f2bf(v.x); o.y = f2bf(v.y); o.z = f2bf(v.z); o.w = f2bf(v.w);
    *(ushort4*)(xb + i) = o;
  } else if (i < XN + WN) {
    int j = i - XN;
    float4 v = *(const float4*)(Wqkv + j);
    ushort4 o; o.x = f2bf(v.x); o.y = f2bf(v.y); o.z = f2bf(v.z); o.w = f2bf(v.w);
    *(ushort4*)(wb + j) = o;
  } else {
    int j = i - XN - WN;      // 0 .. 17407, 4 at a time
    ushort4 o;
    unsigned short t[4];
#pragma unroll
    for (int k = 0; k < 4; ++k)
      t[k] = (j + k < RSZ * HDIM) ? f2bf(Wr[j + k]) : (unsigned short)0;
    o.x = t[0]; o.y = t[1]; o.z = t[2]; o.w = t[3];
    *(ushort4*)(wrb + j) = o;
  }
}

// ------------------- QKV projection GEMM -------------------
__global__ __launch_bounds__(256) void qkv_gemm(const unsigned short* __restrict__ xb,
                                                const unsigned short* __restrict__ wb,
                                                const float* __restrict__ bqkv,
                                                unsigned short* __restrict__ qb,
                                                unsigned short* __restrict__ kbuf,
                                                unsigned short* __restrict__ vtb) {
  __shared__ unsigned short SMEM[2 * 128 * 64];   // As | Bs; reused as Vtmp
  unsigned short* As = SMEM;
  unsigned short* Bs = SMEM + 128 * 64;
  unsigned short* Vtmp = SMEM;                    // 64 x 136 bf16 (17408 B)
  const int tid = threadIdx.x;
  const int m0 = blockIdx.y * 128, n0 = blockIdx.x * 128;
  const int wave = tid >> 6, lane = tid & 63;
  const int q4 = lane >> 4, l16 = lane & 15;
  const int wm = (wave & 1) * 64, wn = (wave >> 1) * 64;
  const int sw = l16 & 7;

  f32x4 acc[4][4];
#pragma unroll
  for (int rt = 0; rt < 4; ++rt)
#pragma unroll
    for (int ct = 0; ct < 4; ++ct) acc[rt][ct] = (f32x4){0.f, 0.f, 0.f, 0.f};

  for (int k0 = 0; k0 < DMOD; k0 += 64) {
#pragma unroll
    for (int it = 0; it < 4; ++it) {
      int ch = it * 256 + tid;
      int r = ch >> 3, cl = (ch & 7) ^ (r & 7);
      gl2lds16(xb + (size_t)(m0 + r) * DMOD + k0 + cl * 8, As + ch * 8);
      gl2lds16(wb + (size_t)(n0 + r) * DMOD + k0 + cl * 8, Bs + ch * 8);
    }
    __syncthreads();
#pragma unroll
    for (int ks = 0; ks < 2; ++ks) {
      bfrag af[4], bf[4];
#pragma unroll
      for (int rt = 0; rt < 4; ++rt)
        af[rt] = *(const bfrag*)(As + (wm + rt * 16 + l16) * 64 + ((ks * 4 + q4) ^ sw) * 8);
#pragma unroll
      for (int ct = 0; ct < 4; ++ct)
        bf[ct] = *(const bfrag*)(Bs + (wn + ct * 16 + l16) * 64 + ((ks * 4 + q4) ^ sw) * 8);
      // swapped order: D rows <- bf rows (n), D cols <- af rows (m)
#pragma unroll
      for (int rt = 0; rt < 4; ++rt)
#pragma unroll
        for (int ct = 0; ct < 4; ++ct)
          acc[rt][ct] = MFMA16(bf[ct], af[rt], acc[rt][ct]);
    }
    __syncthreads();
  }

  // ---- epilogue: lane holds C[m][n..n+3]; m = wm+rt*16+l16, n = wn+ct*16+q4*4
  const int batch = m0 >> 11;
  const int sbase = m0 & 2047;
  const int r3 = blockIdx.x % 3;       // V-region pattern: period 3 tiles
  const bool hasV = (r3 != 0);
  const int nv0 = n0 + ((r3 == 2) ? 64 : 0);   // global col base of V region

#pragma unroll
  for (int ct = 0; ct < 4; ++ct) {
    int ng = n0 + wn + ct * 16 + q4 * 4;
    int hh = ng / 192;
    int rem = ng - hh * 192;
    int t = rem >> 6, dd = rem & 63;
    float4 b4 = *(const float4*)(bqkv + ng);
    if (t < 2) {
      unsigned short* dst = (t == 0) ? qb : kbuf;
      size_t rowo = ((size_t)(batch * NHEAD + hh)) * SEQ + sbase;
#pragma unroll
      for (int rt = 0; rt < 4; ++rt) {
        int m = wm + rt * 16 + l16;
        uint2 pv;
        pv.x = pkbf(acc[rt][ct][0] + b4.x, acc[rt][ct][1] + b4.y);
        pv.y = pkbf(acc[rt][ct][2] + b4.z, acc[rt][ct][3] + b4.w);
        *(uint2*)(dst + (rowo + m) * HDIM + dd) = pv;
      }
    } else {
#pragma unroll
      for (int rt = 0; rt < 4; ++rt) {
        int m = wm + rt * 16 + l16;
        Vtmp[(dd + 0) * 136 + m] = f2bf(acc[rt][ct][0] + b4.x);
        Vtmp[(dd + 1) * 136 + m] = f2bf(acc[rt][ct][1] + b4.y);
        Vtmp[(dd + 2) * 136 + m] = f2bf(acc[rt][ct][2] + b4.z);
        Vtmp[(dd + 3) * 136 + m] = f2bf(acc[rt][ct][3] + b4.w);
      }
    }
  }

  if (hasV) {
    __syncthreads();
    const int hh = nv0 / 192;
    unsigned short* vdst = vtb + ((size_t)(batch * NHEAD + hh)) * HDIM * SEQ;
#pragma unroll
    for (int it = 0; it < 4; ++it) {
      int u = it * 256 + tid;            // dd in [0,64), mc in [0,16)
      int dd = u >> 4, mc = u & 15;
      bfrag val = *(const bfrag*)(Vtmp + dd * 136 + mc * 8);
      *(bfrag*)(vdst + (size_t)dd * SEQ + sbase + mc * 8) = val;
    }
  }
}

// ------------------- rel-pos logits (transposed-D, vector stores) ---------
__global__ __launch_bounds__(256) void rp_gemm(const unsigned short* __restrict__ qb,
                                               const unsigned short* __restrict__ wrb,
                                               const float* __restrict__ br,
                                               unsigned short* __restrict__ rp16) {
  __shared__ unsigned short WrS[RPADN * HDIM];  // 34816 B
  __shared__ unsigned short Qs[64 * HDIM];      // 8192 B
  const int tid = threadIdx.x;
  const size_t row0 = (size_t)blockIdx.x * 64;

  for (int i = tid; i < RPADN * HDIM / 8; i += 256)
    *(uint4*)(&WrS[i * 8]) = *(const uint4*)(&wrb[i * 8]);
  for (int i = tid; i < 512; i += 256)
    *(uint4*)(&Qs[i * 8]) = *(const uint4*)(&qb[row0 * HDIM + i * 8]);
  __syncthreads();

  const int wave = tid >> 6, lane = tid & 63;
  const int q4 = lane >> 4, l16 = lane & 15;

  bfrag af0 = *(const bfrag*)(Qs + (wave * 16 + l16) * 64 + q4 * 8);
  bfrag af1 = *(const bfrag*)(Qs + (wave * 16 + l16) * 64 + 32 + q4 * 8);

  unsigned short* rrow = rp16 + (row0 + wave * 16 + l16) * RSTRIDE;
  const float br256 = br[256];

#pragma unroll 4
  for (int ct = 0; ct < 16; ++ct) {
    f32x4 acc = (f32x4){0.f, 0.f, 0.f, 0.f};
    bfrag w0 = *(const bfrag*)(WrS + (ct * 16 + l16) * 64 + q4 * 8);
    bfrag w1 = *(const bfrag*)(WrS + (ct * 16 + l16) * 64 + 32 + q4 * 8);
    // swapped order: D rows <- Wr rows (r), D cols <- q rows (i)
    acc = MFMA16(w0, af0, acc);
    acc = MFMA16(w1, af1, acc);
    int r = ct * 16 + q4 * 4;
    float4 b4 = *(const float4*)(br + r);
    uint2 pv;
    pv.x = pkbf((acc[0] + b4.x) * LOG2E, (acc[1] + b4.y) * LOG2E);
    pv.y = pkbf((acc[2] + b4.z) * LOG2E, (acc[3] + b4.w) * LOG2E);
    *(uint2*)(rrow + r) = pv;
  }
  // tail tile: only r = 256 is a real column
  {
    f32x4 acc = (f32x4){0.f, 0.f, 0.f, 0.f};
    bfrag w0 = *(const bfrag*)(WrS + (256 + l16) * 64 + q4 * 8);
    bfrag w1 = *(const bfrag*)(WrS + (256 + l16) * 64 + 32 + q4 * 8);
    acc = MFMA16(w0, af0, acc);
    acc = MFMA16(w1, af1, acc);
    if (q4 == 0)
      rrow[256] = f2bf((acc[0] + br256) * LOG2E);
  }
}

// ------------------- flash attention v6: hybrid -------------------
// Round-0 proven core (97us: 2-phase LDS K, wave-private Ps, always-rescale
// softmax) + v5's correctness-validated pieces: XCD remap (FETCH 122->30MB)
// and direct global->VGPR V fragments (PV A-operand == coalesced read of
// transposed V; v5 passed absmax). Structural edit vs round-0:
//   - K double-buffered; STAGE_K(t+1) issued FIRST each iter (T3 ordering),
//     latency hides under QK+softmax of tile t.
//   - V LDS staging deleted (vf loads issued early, consumed by PV ~500cy
//     later; compiler's fine-grained vmcnt covers them).
//   - ONE __syncthreads per iter (was 2): its vmcnt(0) drain only hits
//     loads issued a full compute-phase earlier.
__global__ __launch_bounds__(256) void flash_attn(const unsigned short* __restrict__ qb,
                                                  const unsigned short* __restrict__ kbuf,
                                                  const unsigned short* __restrict__ vtb,
                                                  const unsigned short* __restrict__ rp16,
                                                  float* __restrict__ out) {
  __shared__ unsigned short Ks[2][64 * 64];  // 16384 B, double-buffered
  __shared__ unsigned short Ps[64 * 64];     // 8192 B, wave-private strips
  // total 24576 B

  const int tid = threadIdx.x;
  // XCD remap: XCD g gets heads {4g..4g+3} x all 32 i-tiles -> per-XCD
  // K/V working set = 2 MB, fits the 4 MB per-XCD L2 (required for the
  // per-wave redundant V-fragment reads to stay L2-resident).
  const int orig = blockIdx.x;
  const int slot = orig >> 3;                 // 0..127
  const int bh = (orig & 7) * 4 + (slot >> 5);
  const int i0 = (slot & 31) << 6;
  const int wave = tid >> 6, lane = tid & 63;
  const int q4 = lane >> 4, l16 = lane & 15;
  const int sw = l16 & 7;
  const float SC = 0.125f * LOG2E;

  const int rloc = wave * 16 + l16;
  const int ig = i0 + rloc;                 // this lane's global Q row
  const unsigned short* qrow = qb + ((size_t)bh * SEQ + ig) * HDIM;
  bfrag qf0 = *(const bfrag*)(qrow + q4 * 8);
  bfrag qf1 = *(const bfrag*)(qrow + 32 + q4 * 8);

  const unsigned short* rpbase = rp16 + ((size_t)bh * SEQ + ig) * RSTRIDE;
  const float rpL = bf2f(rpbase[0]);
  const float rpR = bf2f(rpbase[256]);

  float m_s = -3.0e38f, l_s = 0.f;
  f32x4 oacc[4];
#pragma unroll
  for (int ct = 0; ct < 4; ++ct) oacc[ct] = (f32x4){0.f, 0.f, 0.f, 0.f};

  const unsigned short* kbase = kbuf + (size_t)bh * SEQ * HDIM;
  // per-lane base for direct V fragment loads (validated in v5)
  const unsigned short* vfp = vtb + (size_t)bh * HDIM * SEQ + (size_t)l16 * SEQ + q4 * 8;

  // prologue: K(0) into buffer 0 (syncthreads drains vmcnt)
#pragma unroll
  for (int it = 0; it < 2; ++it) {
    int ch = it * 256 + tid;
    int r = ch >> 3, cl = (ch & 7) ^ (r & 7);
    gl2lds16(kbase + (size_t)r * HDIM + cl * 8, &Ks[0][ch * 8]);
  }
  __syncthreads();

  for (int jt = 0; jt < 32; ++jt) {
    const int cur = jt & 1;
    const int j0 = jt * 64;

    // K(t+1) prefetch FIRST: latency hides under QK+softmax of tile t.
    // WAR on Ks[cur^1] protected by the end barrier of iter t-1.
    if (jt < 31) {
#pragma unroll
      for (int it = 0; it < 2; ++it) {
        int ch = it * 256 + tid;
        int r = ch >> 3, cl = (ch & 7) ^ (r & 7);
        gl2lds16(kbase + (size_t)(j0 + 64 + r) * HDIM + cl * 8, &Ks[cur ^ 1][ch * 8]);
      }
    }

    // V(t) fragments direct global->VGPR, issued early; consumed by PV.
    bfrag vf[8];
#pragma unroll
    for (int ct = 0; ct < 4; ++ct) {
      const unsigned short* vr = vfp + (size_t)(ct * 16) * SEQ + j0;
      vf[2 * ct]     = *(const bfrag*)(vr);
      vf[2 * ct + 1] = *(const bfrag*)(vr + 32);
    }

    // S^T = K Q^T : sacc[ct] holds S[j = ct*16+q4*4+reg][i = l16's row]
    f32x4 sacc[4];
#pragma unroll
    for (int ct = 0; ct < 4; ++ct) {
      sacc[ct] = (f32x4){0.f, 0.f, 0.f, 0.f};
      bfrag k0f = *(const bfrag*)(&Ks[cur][(ct * 16 + l16) * 64 + (q4 ^ sw) * 8]);
      bfrag k1f = *(const bfrag*)(&Ks[cur][(ct * 16 + l16) * 64 + ((4 + q4) ^ sw) * 8]);
      sacc[ct] = MFMA16(k0f, qf0, sacc[ct]);
      sacc[ct] = MFMA16(k1f, qf1, sacc[ct]);
    }

    // logits2 = S*(log2e/8) + pos2 ; all 16 of this lane's row in-register
    float p[4][4];
    const int dj = j0 - i0;
    if (dj >= 191) {
#pragma unroll
      for (int ct = 0; ct < 4; ++ct)
#pragma unroll
        for (int reg = 0; reg < 4; ++reg)
          p[ct][reg] = sacc[ct][reg] * SC + rpR;
    } else if (dj <= -191) {
#pragma unroll
      for (int ct = 0; ct < 4; ++ct)
#pragma unroll
        for (int reg = 0; reg < 4; ++reg)
          p[ct][reg] = sacc[ct][reg] * SC + rpL;
    } else {
#pragma unroll
      for (int ct = 0; ct < 4; ++ct) {
#pragma unroll
        for (int reg = 0; reg < 4; ++reg) {
          int j = j0 + ct * 16 + q4 * 4 + reg;
          int off = j - ig;
          off = (off < -128) ? -128 : (off > 128 ? 128 : off);
          p[ct][reg] = sacc[ct][reg] * SC + bf2f(rpbase[off + 128]);
        }
      }
    }

    // online softmax: in-lane tree + xor16/xor32 (quads hold disjoint j's)
    float mm;
    {
      float a0 = fmaxf(fmaxf(p[0][0], p[0][1]), fmaxf(p[0][2], p[0][3]));
      float a1 = fmaxf(fmaxf(p[1][0], p[1][1]), fmaxf(p[1][2], p[1][3]));
      float a2 = fmaxf(fmaxf(p[2][0], p[2][1]), fmaxf(p[2][2], p[2][3]));
      float a3 = fmaxf(fmaxf(p[3][0], p[3][1]), fmaxf(p[3][2], p[3][3]));
      mm = fmaxf(fmaxf(a0, a1), fmaxf(a2, a3));
      mm = fmaxf(mm, __shfl_xor(mm, 16));
      mm = fmaxf(mm, __shfl_xor(mm, 32));
    }
    const float mnew = fmaxf(m_s, mm);
    const float alpha = fexp2(m_s - mnew);
    m_s = mnew;
#pragma unroll
    for (int ct = 0; ct < 4; ++ct)
#pragma unroll
      for (int reg = 0; reg < 4; ++reg)
        p[ct][reg] = fexp2(p[ct][reg] - m_s);
    {
      float s0 = (p[0][0] + p[0][1]) + (p[0][2] + p[0][3]);
      float s1 = (p[1][0] + p[1][1]) + (p[1][2] + p[1][3]);
      float s2 = (p[2][0] + p[2][1]) + (p[2][2] + p[2][3]);
      float s3 = (p[3][0] + p[3][1]) + (p[3][2] + p[3][3]);
      float rs = (s0 + s1) + (s2 + s3);
      rs += __shfl_xor(rs, 16);
      rs += __shfl_xor(rs, 32);
      l_s = l_s * alpha + rs;
    }
#pragma unroll
    for (int ct = 0; ct < 4; ++ct)
#pragma unroll
      for (int reg = 0; reg < 4; ++reg)
        oacc[ct][reg] *= alpha;

    // P^T -> Ps strip (wave-private 16-row strips; same-wave LDS ordering).
    unsigned int* Pw = (unsigned int*)Ps;
#pragma unroll
    for (int ct = 0; ct < 4; ++ct) {
      unsigned int pk01 = pkbf(p[ct][0], p[ct][1]);
      unsigned int pk23 = pkbf(p[ct][2], p[ct][3]);
      int chunk = ct * 2 + (q4 >> 1);
      unsigned int a = rloc * 32 + ((chunk ^ sw) << 2) + ((q4 & 1) << 1);
      Pw[a] = pk01;
      Pw[a + 1] = pk23;
    }

    // PV: out^T += V^T P^T ; pf = B-frag rows = Q rows (read own row)
    bfrag pf0 = *(const bfrag*)(Ps + rloc * 64 + (q4 ^ sw) * 8);
    bfrag pf1 = *(const bfrag*)(Ps + rloc * 64 + ((4 + q4) ^ sw) * 8);
#pragma unroll
    for (int ct = 0; ct < 4; ++ct) {
      oacc[ct] = MFMA16(vf[2 * ct], pf0, oacc[ct]);
      oacc[ct] = MFMA16(vf[2 * ct + 1], pf1, oacc[ct]);
    }

    // single barrier per iter: all waves done reading Ks[cur] before it is
    // restaged at iter t+1; also drains this iter's gl2lds (vmcnt(0)) so
    // the next iter's QK reads Ks[cur^1] safely.
    __syncthreads();
  }

  const int bidx = bh >> 4, hh = bh & 15;
  const float inv = 1.0f / l_s;
  float* orow = out + ((size_t)bidx * SEQ + ig) * DMOD + hh * HDIM;
#pragma unroll
  for (int ct = 0; ct < 4; ++ct) {
    float4 v;
    v.x = oacc[ct][0] * inv;
    v.y = oacc[ct][1] * inv;
    v.z = oacc[ct][2] * inv;
    v.w = oacc[ct][3] * inv;
    *(float4*)(orow + ct * 16 + q4 * 4) = v;
  }
}

// ------------------- launch -------------------
extern "C" void kernel_launch(void* const* d_in, const int* in_sizes, int n_in,
                              void* d_out, int out_size, void* d_ws, size_t ws_size,
                              hipStream_t stream) {
  const float* x    = (const float*)d_in[0];  // [2,2048,1024]
  const float* Wqkv = (const float*)d_in[1];  // [3072,1024]
  const float* bqkv = (const float*)d_in[2];  // [3072]
  const float* Wr   = (const float*)d_in[3];  // [257,64]
  const float* br   = (const float*)d_in[4];  // [257]
  float* out = (float*)d_out;                 // [2,2048,1024] fp32

  char* ws = (char*)d_ws;
  unsigned short* xb   = (unsigned short*)(ws);               // 8 MB
  unsigned short* wb   = (unsigned short*)(ws + 8388608);     // 6 MB
  unsigned short* qb   = (unsigned short*)(ws + 14680064);    // 8 MB
  unsigned short* kb   = (unsigned short*)(ws + 23068672);    // 8 MB
  unsigned short* vtb  = (unsigned short*)(ws + 31457280);    // 8 MB (transposed V)
  unsigned short* wrb  = (unsigned short*)(ws + 39845888);    // 34816 B
  unsigned short* rp16 = (unsigned short*)(ws + 39880704);    // 34.1 MB (bf16, stride 260)

  cast_all<<<7185, 256, 0, stream>>>(x, Wqkv, Wr, xb, wb, wrb);
  qkv_gemm<<<dim3(24, 32), 256, 0, stream>>>(xb, wb, bqkv, qb, kb, vtb);
  rp_gemm<<<1024, 256, 0, stream>>>(qb, wrb, br, rp16);
  flash_attn<<<1024, 256, 0, stream>>>(qb, kb, vtb, rp16, out);
}

// Round 7
// 216.984 us; speedup vs baseline: 1.7387x; 1.3265x over previous
//
#include <hip/hip_runtime.h>

typedef short bfrag __attribute__((ext_vector_type(8)));   // 8 bf16 (4 VGPRs)
typedef float f32x4 __attribute__((ext_vector_type(4)));   // MFMA accumulator

#define MFMA16(a, b, c) __builtin_amdgcn_mfma_f32_16x16x32_bf16((a), (b), (c), 0, 0, 0)

// b=2, s=2048, d=1024, h=16, hd=64, R=257, w=128, scale=sqrt(64)=8
#define SEQ   2048
#define DMOD  1024
#define NHEAD 16
#define HDIM  64
#define RSZ   257
#define RSTRIDE 260   // padded row stride of rp16 (8B-aligned vector stores)
#define RPADN 272     // 17*16, zero-padded
#define XN    (4096*1024)
#define WN    (3072*1024)
#define LOG2E 1.44269504f

__device__ __forceinline__ unsigned short f2bf(float f) {
  unsigned int u = __float_as_uint(f);
  u += 0x7FFFu + ((u >> 16) & 1u);   // round-to-nearest-even
  return (unsigned short)(u >> 16);
}
__device__ __forceinline__ float bf2f(unsigned short u) {
  return __uint_as_float(((unsigned int)u) << 16);
}
// packed f32x2 -> bf16x2 (single v_cvt_pk_bf16_f32 on gfx950)
__device__ __forceinline__ unsigned int pkbf(float a, float b) {
#if defined(__gfx950__)
  unsigned int r;
  asm("v_cvt_pk_bf16_f32 %0, %1, %2" : "=v"(r) : "v"(a), "v"(b));
  return r;
#else
  return (unsigned int)f2bf(a) | ((unsigned int)f2bf(b) << 16);
#endif
}
__device__ __forceinline__ float fexp2(float x) {
#if __has_builtin(__builtin_amdgcn_exp2f)
  return __builtin_amdgcn_exp2f(x);
#else
  return __expf(x * 0.69314718f);
#endif
}
__device__ __forceinline__ void gl2lds16(const void* g, void* l) {
  __builtin_amdgcn_global_load_lds(
      (__attribute__((address_space(1))) void*)(g),
      (__attribute__((address_space(3))) void*)(l), 16, 0, 0);
}

// ------------------- fused cast kernel -------------------
__global__ __launch_bounds__(256) void cast_all(const float* __restrict__ x,
                                                const float* __restrict__ Wqkv,
                                                const float* __restrict__ Wr,
                                                unsigned short* __restrict__ xb,
                                                unsigned short* __restrict__ wb,
                                                unsigned short* __restrict__ wrb) {
  int i = (blockIdx.x * 256 + threadIdx.x) * 4;
  if (i < XN) {
    float4 v = *(const float4*)(x + i);
    ushort4 o; o.x = f2bf(v.x); o.y = f2bf(v.y); o.z = f2bf(v.z); o.w = f2bf(v.w);
    *(ushort4*)(xb + i) = o;
  } else if (i < XN + WN) {
    int j = i - XN;
    float4 v = *(const float4*)(Wqkv + j);
    ushort4 o; o.x = f2bf(v.x); o.y = f2bf(v.y); o.z = f2bf(v.z); o.w = f2bf(v.w);
    *(ushort4*)(wb + j) = o;
  } else {
    int j = i - XN - WN;      // 0 .. 17407, 4 at a time
    ushort4 o;
    unsigned short t[4];
#pragma unroll
    for (int k = 0; k < 4; ++k)
      t[k] = (j + k < RSZ * HDIM) ? f2bf(Wr[j + k]) : (unsigned short)0;
    o.x = t[0]; o.y = t[1]; o.z = t[2]; o.w = t[3];
    *(ushort4*)(wrb + j) = o;
  }
}

// ------------------- QKV projection GEMM -------------------
__global__ __launch_bounds__(256) void qkv_gemm(const unsigned short* __restrict__ xb,
                                                const unsigned short* __restrict__ wb,
                                                const float* __restrict__ bqkv,
                                                unsigned short* __restrict__ qb,
                                                unsigned short* __restrict__ kbuf,
                                                unsigned short* __restrict__ vtb) {
  __shared__ unsigned short SMEM[2 * 128 * 64];   // As | Bs; reused as Vtmp
  unsigned short* As = SMEM;
  unsigned short* Bs = SMEM + 128 * 64;
  unsigned short* Vtmp = SMEM;                    // 64 x 136 bf16 (17408 B)
  const int tid = threadIdx.x;
  const int m0 = blockIdx.y * 128, n0 = blockIdx.x * 128;
  const int wave = tid >> 6, lane = tid & 63;
  const int q4 = lane >> 4, l16 = lane & 15;
  const int wm = (wave & 1) * 64, wn = (wave >> 1) * 64;
  const int sw = l16 & 7;

  f32x4 acc[4][4];
#pragma unroll
  for (int rt = 0; rt < 4; ++rt)
#pragma unroll
    for (int ct = 0; ct < 4; ++ct) acc[rt][ct] = (f32x4){0.f, 0.f, 0.f, 0.f};

  for (int k0 = 0; k0 < DMOD; k0 += 64) {
#pragma unroll
    for (int it = 0; it < 4; ++it) {
      int ch = it * 256 + tid;
      int r = ch >> 3, cl = (ch & 7) ^ (r & 7);
      gl2lds16(xb + (size_t)(m0 + r) * DMOD + k0 + cl * 8, As + ch * 8);
      gl2lds16(wb + (size_t)(n0 + r) * DMOD + k0 + cl * 8, Bs + ch * 8);
    }
    __syncthreads();
#pragma unroll
    for (int ks = 0; ks < 2; ++ks) {
      bfrag af[4], bf[4];
#pragma unroll
      for (int rt = 0; rt < 4; ++rt)
        af[rt] = *(const bfrag*)(As + (wm + rt * 16 + l16) * 64 + ((ks * 4 + q4) ^ sw) * 8);
#pragma unroll
      for (int ct = 0; ct < 4; ++ct)
        bf[ct] = *(const bfrag*)(Bs + (wn + ct * 16 + l16) * 64 + ((ks * 4 + q4) ^ sw) * 8);
      // swapped order: D rows <- bf rows (n), D cols <- af rows (m)
#pragma unroll
      for (int rt = 0; rt < 4; ++rt)
#pragma unroll
        for (int ct = 0; ct < 4; ++ct)
          acc[rt][ct] = MFMA16(bf[ct], af[rt], acc[rt][ct]);
    }
    __syncthreads();
  }

  // ---- epilogue: lane holds C[m][n..n+3]; m = wm+rt*16+l16, n = wn+ct*16+q4*4
  const int batch = m0 >> 11;
  const int sbase = m0 & 2047;
  const int r3 = blockIdx.x % 3;       // V-region pattern: period 3 tiles
  const bool hasV = (r3 != 0);
  const int nv0 = n0 + ((r3 == 2) ? 64 : 0);   // global col base of V region

#pragma unroll
  for (int ct = 0; ct < 4; ++ct) {
    int ng = n0 + wn + ct * 16 + q4 * 4;
    int hh = ng / 192;
    int rem = ng - hh * 192;
    int t = rem >> 6, dd = rem & 63;
    float4 b4 = *(const float4*)(bqkv + ng);
    if (t < 2) {
      unsigned short* dst = (t == 0) ? qb : kbuf;
      size_t rowo = ((size_t)(batch * NHEAD + hh)) * SEQ + sbase;
#pragma unroll
      for (int rt = 0; rt < 4; ++rt) {
        int m = wm + rt * 16 + l16;
        uint2 pv;
        pv.x = pkbf(acc[rt][ct][0] + b4.x, acc[rt][ct][1] + b4.y);
        pv.y = pkbf(acc[rt][ct][2] + b4.z, acc[rt][ct][3] + b4.w);
        *(uint2*)(dst + (rowo + m) * HDIM + dd) = pv;
      }
    } else {
#pragma unroll
      for (int rt = 0; rt < 4; ++rt) {
        int m = wm + rt * 16 + l16;
        Vtmp[(dd + 0) * 136 + m] = f2bf(acc[rt][ct][0] + b4.x);
        Vtmp[(dd + 1) * 136 + m] = f2bf(acc[rt][ct][1] + b4.y);
        Vtmp[(dd + 2) * 136 + m] = f2bf(acc[rt][ct][2] + b4.z);
        Vtmp[(dd + 3) * 136 + m] = f2bf(acc[rt][ct][3] + b4.w);
      }
    }
  }

  if (hasV) {
    __syncthreads();
    const int hh = nv0 / 192;
    unsigned short* vdst = vtb + ((size_t)(batch * NHEAD + hh)) * HDIM * SEQ;
#pragma unroll
    for (int it = 0; it < 4; ++it) {
      int u = it * 256 + tid;            // dd in [0,64), mc in [0,16)
      int dd = u >> 4, mc = u & 15;
      bfrag val = *(const bfrag*)(Vtmp + dd * 136 + mc * 8);
      *(bfrag*)(vdst + (size_t)dd * SEQ + sbase + mc * 8) = val;
    }
  }
}

// ------------------- rel-pos logits (transposed-D, vector stores) ---------
__global__ __launch_bounds__(256) void rp_gemm(const unsigned short* __restrict__ qb,
                                               const unsigned short* __restrict__ wrb,
                                               const float* __restrict__ br,
                                               unsigned short* __restrict__ rp16) {
  __shared__ unsigned short WrS[RPADN * HDIM];  // 34816 B
  __shared__ unsigned short Qs[64 * HDIM];      // 8192 B
  const int tid = threadIdx.x;
  const size_t row0 = (size_t)blockIdx.x * 64;

  for (int i = tid; i < RPADN * HDIM / 8; i += 256)
    *(uint4*)(&WrS[i * 8]) = *(const uint4*)(&wrb[i * 8]);
  for (int i = tid; i < 512; i += 256)
    *(uint4*)(&Qs[i * 8]) = *(const uint4*)(&qb[row0 * HDIM + i * 8]);
  __syncthreads();

  const int wave = tid >> 6, lane = tid & 63;
  const int q4 = lane >> 4, l16 = lane & 15;

  bfrag af0 = *(const bfrag*)(Qs + (wave * 16 + l16) * 64 + q4 * 8);
  bfrag af1 = *(const bfrag*)(Qs + (wave * 16 + l16) * 64 + 32 + q4 * 8);

  unsigned short* rrow = rp16 + (row0 + wave * 16 + l16) * RSTRIDE;
  const float br256 = br[256];

#pragma unroll 4
  for (int ct = 0; ct < 16; ++ct) {
    f32x4 acc = (f32x4){0.f, 0.f, 0.f, 0.f};
    bfrag w0 = *(const bfrag*)(WrS + (ct * 16 + l16) * 64 + q4 * 8);
    bfrag w1 = *(const bfrag*)(WrS + (ct * 16 + l16) * 64 + 32 + q4 * 8);
    // swapped order: D rows <- Wr rows (r), D cols <- q rows (i)
    acc = MFMA16(w0, af0, acc);
    acc = MFMA16(w1, af1, acc);
    int r = ct * 16 + q4 * 4;
    float4 b4 = *(const float4*)(br + r);
    uint2 pv;
    pv.x = pkbf((acc[0] + b4.x) * LOG2E, (acc[1] + b4.y) * LOG2E);
    pv.y = pkbf((acc[2] + b4.z) * LOG2E, (acc[3] + b4.w) * LOG2E);
    *(uint2*)(rrow + r) = pv;
  }
  // tail tile: only r = 256 is a real column
  {
    f32x4 acc = (f32x4){0.f, 0.f, 0.f, 0.f};
    bfrag w0 = *(const bfrag*)(WrS + (256 + l16) * 64 + q4 * 8);
    bfrag w1 = *(const bfrag*)(WrS + (256 + l16) * 64 + 32 + q4 * 8);
    acc = MFMA16(w0, af0, acc);
    acc = MFMA16(w1, af1, acc);
    if (q4 == 0)
      rrow[256] = f2bf((acc[0] + br256) * LOG2E);
  }
}

// ------------------- flash attention v7: 8-wave blocks -------------------
// Round-0 proven structure (2 syncthreads/tile, K+V via gl2lds, wave-private
// Ps strips, in-register softmax) with ONE lever: 512 threads / 128 Q-rows
// per block. 8 waves share each 16KB K/V staging (2x arithmetic intensity
// per staged byte; staging instructions per thread halve), grid 512 = exactly
// 2 blocks/CU -> 16 waves/CU (~50% occupancy vs 33%). Per-wave inner code is
// bit-identical to round 0. LDS: 8K K + 8K V + 16K Ps = 32 KB (2 blocks =
// 64KB, no exact-fit cliff). No remap / no direct-V / no setprio (all
// empirically negative, rounds 1-6). Defer-rescale kept (T13, +5% proven).
__global__ __launch_bounds__(512) void flash_attn(const unsigned short* __restrict__ qb,
                                                  const unsigned short* __restrict__ kbuf,
                                                  const unsigned short* __restrict__ vtb,
                                                  const unsigned short* __restrict__ rp16,
                                                  float* __restrict__ out) {
  __shared__ unsigned short Ks[64 * 64];     // 8192 B
  __shared__ unsigned short Vs[64 * 64];     // 8192 B, [d][j]
  __shared__ unsigned short Ps[128 * 64];    // 16384 B, wave-private strips

  const int tid = threadIdx.x;
  const int i0 = blockIdx.x * 128;
  const int bh = blockIdx.y;
  const int wave = tid >> 6, lane = tid & 63;
  const int q4 = lane >> 4, l16 = lane & 15;
  const int sw = l16 & 7;
  const float SC = 0.125f * LOG2E;

  const int rloc = wave * 16 + l16;          // 0..127
  const int ig = i0 + rloc;                  // this lane's global Q row
  const int iw0 = i0 + wave * 16;            // wave's first q row
  const unsigned short* qrow = qb + ((size_t)bh * SEQ + ig) * HDIM;
  bfrag qf0 = *(const bfrag*)(qrow + q4 * 8);
  bfrag qf1 = *(const bfrag*)(qrow + 32 + q4 * 8);

  const unsigned short* rpbase = rp16 + ((size_t)bh * SEQ + ig) * RSTRIDE;
  const float rpL = bf2f(rpbase[0]);
  const float rpR = bf2f(rpbase[256]);

  float m_s = -3.0e38f, l_s = 0.f;
  f32x4 oacc[4];
#pragma unroll
  for (int ct = 0; ct < 4; ++ct) oacc[ct] = (f32x4){0.f, 0.f, 0.f, 0.f};

  const unsigned short* kbase = kbuf + (size_t)bh * SEQ * HDIM;
  const unsigned short* vbase = vtb + (size_t)bh * HDIM * SEQ;

  for (int jt = 0; jt < 32; ++jt) {
    const int j0 = jt * 64;
    // stage K and V tiles: 512 threads x 16B = 8KB each, one gl2lds16 apiece
    {
      int r = tid >> 3, cl = (tid & 7) ^ (r & 7);
      gl2lds16(kbase + (size_t)(j0 + r) * HDIM + cl * 8, Ks + tid * 8);
      gl2lds16(vbase + (size_t)r * SEQ + j0 + cl * 8, Vs + tid * 8);
    }
    __syncthreads();

    // S^T = K Q^T : sacc[ct] holds S[j = ct*16+q4*4+reg][i = l16's row]
    f32x4 sacc[4];
#pragma unroll
    for (int ct = 0; ct < 4; ++ct) {
      sacc[ct] = (f32x4){0.f, 0.f, 0.f, 0.f};
      bfrag k0f = *(const bfrag*)(Ks + (ct * 16 + l16) * 64 + (q4 ^ sw) * 8);
      bfrag k1f = *(const bfrag*)(Ks + (ct * 16 + l16) * 64 + ((4 + q4) ^ sw) * 8);
      sacc[ct] = MFMA16(k0f, qf0, sacc[ct]);
      sacc[ct] = MFMA16(k1f, qf1, sacc[ct]);
    }

    // logits2 = S*(log2e/8) + pos2 ; per-wave saturation bounds (v6-validated)
    float p[4][4];
    const int djw = j0 - iw0;
    if (djw >= 143) {            // j0 - (iw0+15) >= 128 -> all clamp +128
#pragma unroll
      for (int ct = 0; ct < 4; ++ct)
#pragma unroll
        for (int reg = 0; reg < 4; ++reg)
          p[ct][reg] = sacc[ct][reg] * SC + rpR;
    } else if (djw <= -191) {    // j0+63 - iw0 <= -128 -> all clamp -128
#pragma unroll
      for (int ct = 0; ct < 4; ++ct)
#pragma unroll
        for (int reg = 0; reg < 4; ++reg)
          p[ct][reg] = sacc[ct][reg] * SC + rpL;
    } else {
#pragma unroll
      for (int ct = 0; ct < 4; ++ct) {
#pragma unroll
        for (int reg = 0; reg < 4; ++reg) {
          int j = j0 + ct * 16 + q4 * 4 + reg;
          int off = j - ig;
          off = (off < -128) ? -128 : (off > 128 ? 128 : off);
          p[ct][reg] = sacc[ct][reg] * SC + bf2f(rpbase[off + 128]);
        }
      }
    }

    // online softmax: in-lane tree + xor16/xor32 (quads hold disjoint j's)
    float mm;
    {
      float a0 = fmaxf(fmaxf(p[0][0], p[0][1]), fmaxf(p[0][2], p[0][3]));
      float a1 = fmaxf(fmaxf(p[1][0], p[1][1]), fmaxf(p[1][2], p[1][3]));
      float a2 = fmaxf(fmaxf(p[2][0], p[2][1]), fmaxf(p[2][2], p[2][3]));
      float a3 = fmaxf(fmaxf(p[3][0], p[3][1]), fmaxf(p[3][2], p[3][3]));
      mm = fmaxf(fmaxf(a0, a1), fmaxf(a2, a3));
      mm = fmaxf(mm, __shfl_xor(mm, 16));
      mm = fmaxf(mm, __shfl_xor(mm, 32));
    }
    // defer-rescale (T13): skip O-rescale when max grows by <= 8 (log2 units)
    if (!__all(mm <= m_s + 8.0f)) {
      const float mnew = fmaxf(m_s, mm);
      const float alpha = fexp2(m_s - mnew);
      m_s = mnew;
      l_s *= alpha;
#pragma unroll
      for (int ct = 0; ct < 4; ++ct)
#pragma unroll
        for (int reg = 0; reg < 4; ++reg)
          oacc[ct][reg] *= alpha;
    }
#pragma unroll
    for (int ct = 0; ct < 4; ++ct)
#pragma unroll
      for (int reg = 0; reg < 4; ++reg)
        p[ct][reg] = fexp2(p[ct][reg] - m_s);
    {
      float s0 = (p[0][0] + p[0][1]) + (p[0][2] + p[0][3]);
      float s1 = (p[1][0] + p[1][1]) + (p[1][2] + p[1][3]);
      float s2 = (p[2][0] + p[2][1]) + (p[2][2] + p[2][3]);
      float s3 = (p[3][0] + p[3][1]) + (p[3][2] + p[3][3]);
      float rs = (s0 + s1) + (s2 + s3);
      rs += __shfl_xor(rs, 16);
      rs += __shfl_xor(rs, 32);
      l_s += rs;
    }

    // P^T -> Ps strip (wave-private 16-row strips; same-wave LDS ordering)
    unsigned int* Pw = (unsigned int*)Ps;
#pragma unroll
    for (int ct = 0; ct < 4; ++ct) {
      unsigned int pk01 = pkbf(p[ct][0], p[ct][1]);
      unsigned int pk23 = pkbf(p[ct][2], p[ct][3]);
      int chunk = ct * 2 + (q4 >> 1);
      unsigned int a = rloc * 32 + ((chunk ^ sw) << 2) + ((q4 & 1) << 1);
      Pw[a] = pk01;
      Pw[a + 1] = pk23;
    }

    // PV: out^T += V^T P^T ; pf = B-frag rows = Q rows (read own row)
    bfrag pf0 = *(const bfrag*)(Ps + rloc * 64 + (q4 ^ sw) * 8);
    bfrag pf1 = *(const bfrag*)(Ps + rloc * 64 + ((4 + q4) ^ sw) * 8);
#pragma unroll
    for (int ct = 0; ct < 4; ++ct) {
      bfrag v0f = *(const bfrag*)(Vs + (ct * 16 + l16) * 64 + (q4 ^ sw) * 8);
      bfrag v1f = *(const bfrag*)(Vs + (ct * 16 + l16) * 64 + ((4 + q4) ^ sw) * 8);
      oacc[ct] = MFMA16(v0f, pf0, oacc[ct]);
      oacc[ct] = MFMA16(v1f, pf1, oacc[ct]);
    }
    __syncthreads();
  }

  const int bidx = bh >> 4, hh = bh & 15;
  const float inv = 1.0f / l_s;
  float* orow = out + ((size_t)bidx * SEQ + ig) * DMOD + hh * HDIM;
#pragma unroll
  for (int ct = 0; ct < 4; ++ct) {
    float4 v;
    v.x = oacc[ct][0] * inv;
    v.y = oacc[ct][1] * inv;
    v.z = oacc[ct][2] * inv;
    v.w = oacc[ct][3] * inv;
    *(float4*)(orow + ct * 16 + q4 * 4) = v;
  }
}

// ------------------- launch -------------------
extern "C" void kernel_launch(void* const* d_in, const int* in_sizes, int n_in,
                              void* d_out, int out_size, void* d_ws, size_t ws_size,
                              hipStream_t stream) {
  const float* x    = (const float*)d_in[0];  // [2,2048,1024]
  const float* Wqkv = (const float*)d_in[1];  // [3072,1024]
  const float* bqkv = (const float*)d_in[2];  // [3072]
  const float* Wr   = (const float*)d_in[3];  // [257,64]
  const float* br   = (const float*)d_in[4];  // [257]
  float* out = (float*)d_out;                 // [2,2048,1024] fp32

  char* ws = (char*)d_ws;
  unsigned short* xb   = (unsigned short*)(ws);               // 8 MB
  unsigned short* wb   = (unsigned short*)(ws + 8388608);     // 6 MB
  unsigned short* qb   = (unsigned short*)(ws + 14680064);    // 8 MB
  unsigned short* kb   = (unsigned short*)(ws + 23068672);    // 8 MB
  unsigned short* vtb  = (unsigned short*)(ws + 31457280);    // 8 MB (transposed V)
  unsigned short* wrb  = (unsigned short*)(ws + 39845888);    // 34816 B
  unsigned short* rp16 = (unsigned short*)(ws + 39880704);    // 34.1 MB (bf16, stride 260)

  cast_all<<<7185, 256, 0, stream>>>(x, Wqkv, Wr, xb, wb, wrb);
  qkv_gemm<<<dim3(24, 32), 256, 0, stream>>>(xb, wb, bqkv, qb, kb, vtb);
  rp_gemm<<<1024, 256, 0, stream>>>(qb, wrb, br, rp16);
  flash_attn<<<dim3(16, 32), 512, 0, stream>>>(qb, kb, vtb, rp16, out);
}

// Round 8
// 215.180 us; speedup vs baseline: 1.7532x; 1.0084x over previous
//
#include <hip/hip_runtime.h>

typedef short bfrag __attribute__((ext_vector_type(8)));   // 8 bf16 (4 VGPRs)
typedef float f32x4 __attribute__((ext_vector_type(4)));   // MFMA accumulator

#define MFMA16(a, b, c) __builtin_amdgcn_mfma_f32_16x16x32_bf16((a), (b), (c), 0, 0, 0)

// b=2, s=2048, d=1024, h=16, hd=64, R=257, w=128, scale=sqrt(64)=8
#define SEQ   2048
#define DMOD  1024
#define NHEAD 16
#define HDIM  64
#define RSZ   257
#define RSTRIDE 260   // padded row stride of rp16 (8B-aligned vector stores)
#define RPADN 272     // 17*16, zero-padded
#define XN    (4096*1024)
#define WN    (3072*1024)
#define LOG2E 1.44269504f

__device__ __forceinline__ unsigned short f2bf(float f) {
  unsigned int u = __float_as_uint(f);
  u += 0x7FFFu + ((u >> 16) & 1u);   // round-to-nearest-even
  return (unsigned short)(u >> 16);
}
__device__ __forceinline__ float bf2f(unsigned short u) {
  return __uint_as_float(((unsigned int)u) << 16);
}
// packed f32x2 -> bf16x2 (single v_cvt_pk_bf16_f32 on gfx950)
__device__ __forceinline__ unsigned int pkbf(float a, float b) {
#if defined(__gfx950__)
  unsigned int r;
  asm("v_cvt_pk_bf16_f32 %0, %1, %2" : "=v"(r) : "v"(a), "v"(b));
  return r;
#else
  return (unsigned int)f2bf(a) | ((unsigned int)f2bf(b) << 16);
#endif
}
__device__ __forceinline__ float fexp2(float x) {
#if __has_builtin(__builtin_amdgcn_exp2f)
  return __builtin_amdgcn_exp2f(x);
#else
  return __expf(x * 0.69314718f);
#endif
}
__device__ __forceinline__ void gl2lds16(const void* g, void* l) {
  __builtin_amdgcn_global_load_lds(
      (__attribute__((address_space(1))) void*)(g),
      (__attribute__((address_space(3))) void*)(l), 16, 0, 0);
}

// ------------------- fused cast kernel -------------------
__global__ __launch_bounds__(256) void cast_all(const float* __restrict__ x,
                                                const float* __restrict__ Wqkv,
                                                const float* __restrict__ Wr,
                                                unsigned short* __restrict__ xb,
                                                unsigned short* __restrict__ wb,
                                                unsigned short* __restrict__ wrb) {
  int i = (blockIdx.x * 256 + threadIdx.x) * 4;
  if (i < XN) {
    float4 v = *(const float4*)(x + i);
    ushort4 o; o.x = f2bf(v.x); o.y = f2bf(v.y); o.z = f2bf(v.z); o.w = f2bf(v.w);
    *(ushort4*)(xb + i) = o;
  } else if (i < XN + WN) {
    int j = i - XN;
    float4 v = *(const float4*)(Wqkv + j);
    ushort4 o; o.x = f2bf(v.x); o.y = f2bf(v.y); o.z = f2bf(v.z); o.w = f2bf(v.w);
    *(ushort4*)(wb + j) = o;
  } else {
    int j = i - XN - WN;      // 0 .. 17407, 4 at a time
    ushort4 o;
    unsigned short t[4];
#pragma unroll
    for (int k = 0; k < 4; ++k)
      t[k] = (j + k < RSZ * HDIM) ? f2bf(Wr[j + k]) : (unsigned short)0;
    o.x = t[0]; o.y = t[1]; o.z = t[2]; o.w = t[3];
    *(ushort4*)(wrb + j) = o;
  }
}

// ------------------- QKV projection GEMM -------------------
__global__ __launch_bounds__(256) void qkv_gemm(const unsigned short* __restrict__ xb,
                                                const unsigned short* __restrict__ wb,
                                                const float* __restrict__ bqkv,
                                                unsigned short* __restrict__ qb,
                                                unsigned short* __restrict__ kbuf,
                                                unsigned short* __restrict__ vtb) {
  __shared__ unsigned short SMEM[2 * 128 * 64];   // As | Bs; reused as Vtmp
  unsigned short* As = SMEM;
  unsigned short* Bs = SMEM + 128 * 64;
  unsigned short* Vtmp = SMEM;                    // 64 x 136 bf16 (17408 B)
  const int tid = threadIdx.x;
  const int m0 = blockIdx.y * 128, n0 = blockIdx.x * 128;
  const int wave = tid >> 6, lane = tid & 63;
  const int q4 = lane >> 4, l16 = lane & 15;
  const int wm = (wave & 1) * 64, wn = (wave >> 1) * 64;
  const int sw = l16 & 7;

  f32x4 acc[4][4];
#pragma unroll
  for (int rt = 0; rt < 4; ++rt)
#pragma unroll
    for (int ct = 0; ct < 4; ++ct) acc[rt][ct] = (f32x4){0.f, 0.f, 0.f, 0.f};

  for (int k0 = 0; k0 < DMOD; k0 += 64) {
#pragma unroll
    for (int it = 0; it < 4; ++it) {
      int ch = it * 256 + tid;
      int r = ch >> 3, cl = (ch & 7) ^ (r & 7);
      gl2lds16(xb + (size_t)(m0 + r) * DMOD + k0 + cl * 8, As + ch * 8);
      gl2lds16(wb + (size_t)(n0 + r) * DMOD + k0 + cl * 8, Bs + ch * 8);
    }
    __syncthreads();
#pragma unroll
    for (int ks = 0; ks < 2; ++ks) {
      bfrag af[4], bf[4];
#pragma unroll
      for (int rt = 0; rt < 4; ++rt)
        af[rt] = *(const bfrag*)(As + (wm + rt * 16 + l16) * 64 + ((ks * 4 + q4) ^ sw) * 8);
#pragma unroll
      for (int ct = 0; ct < 4; ++ct)
        bf[ct] = *(const bfrag*)(Bs + (wn + ct * 16 + l16) * 64 + ((ks * 4 + q4) ^ sw) * 8);
      // swapped order: D rows <- bf rows (n), D cols <- af rows (m)
#pragma unroll
      for (int rt = 0; rt < 4; ++rt)
#pragma unroll
        for (int ct = 0; ct < 4; ++ct)
          acc[rt][ct] = MFMA16(bf[ct], af[rt], acc[rt][ct]);
    }
    __syncthreads();
  }

  // ---- epilogue: lane holds C[m][n..n+3]; m = wm+rt*16+l16, n = wn+ct*16+q4*4
  const int batch = m0 >> 11;
  const int sbase = m0 & 2047;
  const int r3 = blockIdx.x % 3;       // V-region pattern: period 3 tiles
  const bool hasV = (r3 != 0);
  const int nv0 = n0 + ((r3 == 2) ? 64 : 0);   // global col base of V region

#pragma unroll
  for (int ct = 0; ct < 4; ++ct) {
    int ng = n0 + wn + ct * 16 + q4 * 4;
    int hh = ng / 192;
    int rem = ng - hh * 192;
    int t = rem >> 6, dd = rem & 63;
    float4 b4 = *(const float4*)(bqkv + ng);
    if (t < 2) {
      unsigned short* dst = (t == 0) ? qb : kbuf;
      size_t rowo = ((size_t)(batch * NHEAD + hh)) * SEQ + sbase;
#pragma unroll
      for (int rt = 0; rt < 4; ++rt) {
        int m = wm + rt * 16 + l16;
        uint2 pv;
        pv.x = pkbf(acc[rt][ct][0] + b4.x, acc[rt][ct][1] + b4.y);
        pv.y = pkbf(acc[rt][ct][2] + b4.z, acc[rt][ct][3] + b4.w);
        *(uint2*)(dst + (rowo + m) * HDIM + dd) = pv;
      }
    } else {
#pragma unroll
      for (int rt = 0; rt < 4; ++rt) {
        int m = wm + rt * 16 + l16;
        Vtmp[(dd + 0) * 136 + m] = f2bf(acc[rt][ct][0] + b4.x);
        Vtmp[(dd + 1) * 136 + m] = f2bf(acc[rt][ct][1] + b4.y);
        Vtmp[(dd + 2) * 136 + m] = f2bf(acc[rt][ct][2] + b4.z);
        Vtmp[(dd + 3) * 136 + m] = f2bf(acc[rt][ct][3] + b4.w);
      }
    }
  }

  if (hasV) {
    __syncthreads();
    const int hh = nv0 / 192;
    unsigned short* vdst = vtb + ((size_t)(batch * NHEAD + hh)) * HDIM * SEQ;
#pragma unroll
    for (int it = 0; it < 4; ++it) {
      int u = it * 256 + tid;            // dd in [0,64), mc in [0,16)
      int dd = u >> 4, mc = u & 15;
      bfrag val = *(const bfrag*)(Vtmp + dd * 136 + mc * 8);
      *(bfrag*)(vdst + (size_t)dd * SEQ + sbase + mc * 8) = val;
    }
  }
}

// ------------------- rel-pos logits (transposed-D, vector stores) ---------
__global__ __launch_bounds__(256) void rp_gemm(const unsigned short* __restrict__ qb,
                                               const unsigned short* __restrict__ wrb,
                                               const float* __restrict__ br,
                                               unsigned short* __restrict__ rp16) {
  __shared__ unsigned short WrS[RPADN * HDIM];  // 34816 B
  __shared__ unsigned short Qs[64 * HDIM];      // 8192 B
  const int tid = threadIdx.x;
  const size_t row0 = (size_t)blockIdx.x * 64;

  for (int i = tid; i < RPADN * HDIM / 8; i += 256)
    *(uint4*)(&WrS[i * 8]) = *(const uint4*)(&wrb[i * 8]);
  for (int i = tid; i < 512; i += 256)
    *(uint4*)(&Qs[i * 8]) = *(const uint4*)(&qb[row0 * HDIM + i * 8]);
  __syncthreads();

  const int wave = tid >> 6, lane = tid & 63;
  const int q4 = lane >> 4, l16 = lane & 15;

  bfrag af0 = *(const bfrag*)(Qs + (wave * 16 + l16) * 64 + q4 * 8);
  bfrag af1 = *(const bfrag*)(Qs + (wave * 16 + l16) * 64 + 32 + q4 * 8);

  unsigned short* rrow = rp16 + (row0 + wave * 16 + l16) * RSTRIDE;
  const float br256 = br[256];

#pragma unroll 4
  for (int ct = 0; ct < 16; ++ct) {
    f32x4 acc = (f32x4){0.f, 0.f, 0.f, 0.f};
    bfrag w0 = *(const bfrag*)(WrS + (ct * 16 + l16) * 64 + q4 * 8);
    bfrag w1 = *(const bfrag*)(WrS + (ct * 16 + l16) * 64 + 32 + q4 * 8);
    // swapped order: D rows <- Wr rows (r), D cols <- q rows (i)
    acc = MFMA16(w0, af0, acc);
    acc = MFMA16(w1, af1, acc);
    int r = ct * 16 + q4 * 4;
    float4 b4 = *(const float4*)(br + r);
    uint2 pv;
    pv.x = pkbf((acc[0] + b4.x) * LOG2E, (acc[1] + b4.y) * LOG2E);
    pv.y = pkbf((acc[2] + b4.z) * LOG2E, (acc[3] + b4.w) * LOG2E);
    *(uint2*)(rrow + r) = pv;
  }
  // tail tile: only r = 256 is a real column
  {
    f32x4 acc = (f32x4){0.f, 0.f, 0.f, 0.f};
    bfrag w0 = *(const bfrag*)(WrS + (256 + l16) * 64 + q4 * 8);
    bfrag w1 = *(const bfrag*)(WrS + (256 + l16) * 64 + 32 + q4 * 8);
    acc = MFMA16(w0, af0, acc);
    acc = MFMA16(w1, af1, acc);
    if (q4 == 0)
      rrow[256] = f2bf((acc[0] + br256) * LOG2E);
  }
}

// ------------------- flash attention v8: 8-wave blocks + XCD remap -------
// v7 (90.3us, proven: 512 threads / 128 Q-rows, shared 16KB K/V staging,
// wave-private Ps, defer-rescale) with ONE isolated change: XCD-aware
// block remap. v7's dim3(16,32) grid round-robins XCDs by linear id so
// each XCD touched all 32 bh (16 MB >> 4 MB L2 -> FETCH 120 MB, staging
// drain at L3/HBM latency). Remap gives XCD g the 4 heads {4g..4g+3} x
// all 16 i-blocks -> 2 MB per-XCD working set, L2-resident staging.
// Grid 512 % 8 == 0 -> bijective. Everything else byte-identical to v7.
__global__ __launch_bounds__(512) void flash_attn(const unsigned short* __restrict__ qb,
                                                  const unsigned short* __restrict__ kbuf,
                                                  const unsigned short* __restrict__ vtb,
                                                  const unsigned short* __restrict__ rp16,
                                                  float* __restrict__ out) {
  __shared__ unsigned short Ks[64 * 64];     // 8192 B
  __shared__ unsigned short Vs[64 * 64];     // 8192 B, [d][j]
  __shared__ unsigned short Ps[128 * 64];    // 16384 B, wave-private strips

  const int tid = threadIdx.x;
  const int orig = blockIdx.x;               // 0..511
  const int slot = orig >> 3;                // 0..63
  const int bh = (orig & 7) * 4 + (slot >> 4);
  const int i0 = (slot & 15) << 7;           // 16 i-blocks x 128 rows
  const int wave = tid >> 6, lane = tid & 63;
  const int q4 = lane >> 4, l16 = lane & 15;
  const int sw = l16 & 7;
  const float SC = 0.125f * LOG2E;

  const int rloc = wave * 16 + l16;          // 0..127
  const int ig = i0 + rloc;                  // this lane's global Q row
  const int iw0 = i0 + wave * 16;            // wave's first q row
  const unsigned short* qrow = qb + ((size_t)bh * SEQ + ig) * HDIM;
  bfrag qf0 = *(const bfrag*)(qrow + q4 * 8);
  bfrag qf1 = *(const bfrag*)(qrow + 32 + q4 * 8);

  const unsigned short* rpbase = rp16 + ((size_t)bh * SEQ + ig) * RSTRIDE;
  const float rpL = bf2f(rpbase[0]);
  const float rpR = bf2f(rpbase[256]);

  float m_s = -3.0e38f, l_s = 0.f;
  f32x4 oacc[4];
#pragma unroll
  for (int ct = 0; ct < 4; ++ct) oacc[ct] = (f32x4){0.f, 0.f, 0.f, 0.f};

  const unsigned short* kbase = kbuf + (size_t)bh * SEQ * HDIM;
  const unsigned short* vbase = vtb + (size_t)bh * HDIM * SEQ;

  for (int jt = 0; jt < 32; ++jt) {
    const int j0 = jt * 64;
    // stage K and V tiles: 512 threads x 16B = 8KB each, one gl2lds16 apiece
    {
      int r = tid >> 3, cl = (tid & 7) ^ (r & 7);
      gl2lds16(kbase + (size_t)(j0 + r) * HDIM + cl * 8, Ks + tid * 8);
      gl2lds16(vbase + (size_t)r * SEQ + j0 + cl * 8, Vs + tid * 8);
    }
    __syncthreads();

    // S^T = K Q^T : sacc[ct] holds S[j = ct*16+q4*4+reg][i = l16's row]
    f32x4 sacc[4];
#pragma unroll
    for (int ct = 0; ct < 4; ++ct) {
      sacc[ct] = (f32x4){0.f, 0.f, 0.f, 0.f};
      bfrag k0f = *(const bfrag*)(Ks + (ct * 16 + l16) * 64 + (q4 ^ sw) * 8);
      bfrag k1f = *(const bfrag*)(Ks + (ct * 16 + l16) * 64 + ((4 + q4) ^ sw) * 8);
      sacc[ct] = MFMA16(k0f, qf0, sacc[ct]);
      sacc[ct] = MFMA16(k1f, qf1, sacc[ct]);
    }

    // logits2 = S*(log2e/8) + pos2 ; per-wave saturation bounds
    float p[4][4];
    const int djw = j0 - iw0;
    if (djw >= 143) {            // j0 - (iw0+15) >= 128 -> all clamp +128
#pragma unroll
      for (int ct = 0; ct < 4; ++ct)
#pragma unroll
        for (int reg = 0; reg < 4; ++reg)
          p[ct][reg] = sacc[ct][reg] * SC + rpR;
    } else if (djw <= -191) {    // j0+63 - iw0 <= -128 -> all clamp -128
#pragma unroll
      for (int ct = 0; ct < 4; ++ct)
#pragma unroll
        for (int reg = 0; reg < 4; ++reg)
          p[ct][reg] = sacc[ct][reg] * SC + rpL;
    } else {
#pragma unroll
      for (int ct = 0; ct < 4; ++ct) {
#pragma unroll
        for (int reg = 0; reg < 4; ++reg) {
          int j = j0 + ct * 16 + q4 * 4 + reg;
          int off = j - ig;
          off = (off < -128) ? -128 : (off > 128 ? 128 : off);
          p[ct][reg] = sacc[ct][reg] * SC + bf2f(rpbase[off + 128]);
        }
      }
    }

    // online softmax: in-lane tree + xor16/xor32 (quads hold disjoint j's)
    float mm;
    {
      float a0 = fmaxf(fmaxf(p[0][0], p[0][1]), fmaxf(p[0][2], p[0][3]));
      float a1 = fmaxf(fmaxf(p[1][0], p[1][1]), fmaxf(p[1][2], p[1][3]));
      float a2 = fmaxf(fmaxf(p[2][0], p[2][1]), fmaxf(p[2][2], p[2][3]));
      float a3 = fmaxf(fmaxf(p[3][0], p[3][1]), fmaxf(p[3][2], p[3][3]));
      mm = fmaxf(fmaxf(a0, a1), fmaxf(a2, a3));
      mm = fmaxf(mm, __shfl_xor(mm, 16));
      mm = fmaxf(mm, __shfl_xor(mm, 32));
    }
    // defer-rescale (T13): skip O-rescale when max grows by <= 8 (log2 units)
    if (!__all(mm <= m_s + 8.0f)) {
      const float mnew = fmaxf(m_s, mm);
      const float alpha = fexp2(m_s - mnew);
      m_s = mnew;
      l_s *= alpha;
#pragma unroll
      for (int ct = 0; ct < 4; ++ct)
#pragma unroll
        for (int reg = 0; reg < 4; ++reg)
          oacc[ct][reg] *= alpha;
    }
#pragma unroll
    for (int ct = 0; ct < 4; ++ct)
#pragma unroll
      for (int reg = 0; reg < 4; ++reg)
        p[ct][reg] = fexp2(p[ct][reg] - m_s);
    {
      float s0 = (p[0][0] + p[0][1]) + (p[0][2] + p[0][3]);
      float s1 = (p[1][0] + p[1][1]) + (p[1][2] + p[1][3]);
      float s2 = (p[2][0] + p[2][1]) + (p[2][2] + p[2][3]);
      float s3 = (p[3][0] + p[3][1]) + (p[3][2] + p[3][3]);
      float rs = (s0 + s1) + (s2 + s3);
      rs += __shfl_xor(rs, 16);
      rs += __shfl_xor(rs, 32);
      l_s += rs;
    }

    // P^T -> Ps strip (wave-private 16-row strips; same-wave LDS ordering)
    unsigned int* Pw = (unsigned int*)Ps;
#pragma unroll
    for (int ct = 0; ct < 4; ++ct) {
      unsigned int pk01 = pkbf(p[ct][0], p[ct][1]);
      unsigned int pk23 = pkbf(p[ct][2], p[ct][3]);
      int chunk = ct * 2 + (q4 >> 1);
      unsigned int a = rloc * 32 + ((chunk ^ sw) << 2) + ((q4 & 1) << 1);
      Pw[a] = pk01;
      Pw[a + 1] = pk23;
    }

    // PV: out^T += V^T P^T ; pf = B-frag rows = Q rows (read own row)
    bfrag pf0 = *(const bfrag*)(Ps + rloc * 64 + (q4 ^ sw) * 8);
    bfrag pf1 = *(const bfrag*)(Ps + rloc * 64 + ((4 + q4) ^ sw) * 8);
#pragma unroll
    for (int ct = 0; ct < 4; ++ct) {
      bfrag v0f = *(const bfrag*)(Vs + (ct * 16 + l16) * 64 + (q4 ^ sw) * 8);
      bfrag v1f = *(const bfrag*)(Vs + (ct * 16 + l16) * 64 + ((4 + q4) ^ sw) * 8);
      oacc[ct] = MFMA16(v0f, pf0, oacc[ct]);
      oacc[ct] = MFMA16(v1f, pf1, oacc[ct]);
    }
    __syncthreads();
  }

  const int bidx = bh >> 4, hh = bh & 15;
  const float inv = 1.0f / l_s;
  float* orow = out + ((size_t)bidx * SEQ + ig) * DMOD + hh * HDIM;
#pragma unroll
  for (int ct = 0; ct < 4; ++ct) {
    float4 v;
    v.x = oacc[ct][0] * inv;
    v.y = oacc[ct][1] * inv;
    v.z = oacc[ct][2] * inv;
    v.w = oacc[ct][3] * inv;
    *(float4*)(orow + ct * 16 + q4 * 4) = v;
  }
}

// ------------------- launch -------------------
extern "C" void kernel_launch(void* const* d_in, const int* in_sizes, int n_in,
                              void* d_out, int out_size, void* d_ws, size_t ws_size,
                              hipStream_t stream) {
  const float* x    = (const float*)d_in[0];  // [2,2048,1024]
  const float* Wqkv = (const float*)d_in[1];  // [3072,1024]
  const float* bqkv = (const float*)d_in[2];  // [3072]
  const float* Wr   = (const float*)d_in[3];  // [257,64]
  const float* br   = (const float*)d_in[4];  // [257]
  float* out = (float*)d_out;                 // [2,2048,1024] fp32

  char* ws = (char*)d_ws;
  unsigned short* xb   = (unsigned short*)(ws);               // 8 MB
  unsigned short* wb   = (unsigned short*)(ws + 8388608);     // 6 MB
  unsigned short* qb   = (unsigned short*)(ws + 14680064);    // 8 MB
  unsigned short* kb   = (unsigned short*)(ws + 23068672);    // 8 MB
  unsigned short* vtb  = (unsigned short*)(ws + 31457280);    // 8 MB (transposed V)
  unsigned short* wrb  = (unsigned short*)(ws + 39845888);    // 34816 B
  unsigned short* rp16 = (unsigned short*)(ws + 39880704);    // 34.1 MB (bf16, stride 260)

  cast_all<<<7185, 256, 0, stream>>>(x, Wqkv, Wr, xb, wb, wrb);
  qkv_gemm<<<dim3(24, 32), 256, 0, stream>>>(xb, wb, bqkv, qb, kb, vtb);
  rp_gemm<<<1024, 256, 0, stream>>>(qb, wrb, br, rp16);
  flash_attn<<<512, 512, 0, stream>>>(qb, kb, vtb, rp16, out);
}